// Round 1
// baseline (198.331 us; speedup 1.0000x reference)
//
#include <hip/hip_runtime.h>
#include <math.h>

#define L 1024
#define NB 32
#define DD 256
#define LAM_F 0.2f
#define EPS_F 1e-7f

__device__ __forceinline__ float wave_reduce_sum(float v) {
#pragma unroll
    for (int m = 1; m < 64; m <<= 1) v += __shfl_xor(v, m, 64);
    return v;
}

// Kernel A1: per row i of item b, compute ||x_i||^2, ||y_i||^2, and the 5 band
// dot products x_i . y_{i+o}, o in [-2,2]. One wave (64 lanes x float4 = 256
// floats = D) per row. Grid = 32 items * 256 chunks, 4 waves/block.
__global__ void __launch_bounds__(256) norms_dots_kernel(
        const float* __restrict__ m1, const float* __restrict__ m2,
        float* __restrict__ dots, float* __restrict__ xn2o, float* __restrict__ yn2o) {
    const int wave = threadIdx.x >> 6, lane = threadIdx.x & 63;
    const int blk = blockIdx.x;
    const int b = blk >> 8;                    // 256 chunks per item
    const int i = ((blk & 255) << 2) | wave;   // row index
    const float4 xv = ((const float4*)(m1 + (size_t)(i * NB + b) * DD))[lane];
    float xn2 = xv.x * xv.x + xv.y * xv.y + xv.z * xv.z + xv.w * xv.w;
    float yn2 = 0.f;
    float dt[5];
#pragma unroll
    for (int o = 0; o < 5; ++o) {
        int j = i + o - 2;
        float d = 0.f;
        if (j >= 0 && j < L) {
            const float4 yv = ((const float4*)(m2 + (size_t)(j * NB + b) * DD))[lane];
            d = xv.x * yv.x + xv.y * yv.y + xv.z * yv.z + xv.w * yv.w;
            if (o == 2) yn2 = yv.x * yv.x + yv.y * yv.y + yv.z * yv.z + yv.w * yv.w;
        }
        dt[o] = d;
    }
    xn2 = wave_reduce_sum(xn2);
    yn2 = wave_reduce_sum(yn2);
#pragma unroll
    for (int o = 0; o < 5; ++o) dt[o] = wave_reduce_sum(dt[o]);
    if (lane == 0) {
        const int r = b * L + i;
        xn2o[r] = xn2;
        yn2o[r] = yn2;
#pragma unroll
        for (int o = 0; o < 5; ++o) dots[r * 5 + o] = dt[o];
    }
}

// Kernel A2: one block per batch item, thread i owns row i. Banded Sinkhorn in
// LDS, faithful to the reference semantics (incl. the column-correction-
// applied-along-rows quirk and the cond/active early stop).
__global__ void __launch_bounds__(1024) sinkhorn_kernel(
        const float* __restrict__ dots, const float* __restrict__ xn2,
        const float* __restrict__ yn2, const int* __restrict__ lengths,
        float* __restrict__ oband, float* __restrict__ cost_out) {
    __shared__ float Pb[L * 5];
    __shared__ float Mb[L * 5];
    __shared__ float inv_ny[L];
    __shared__ float u[L];
    __shared__ float rs[L];
    __shared__ float red[16];

    const int b = blockIdx.x;
    const int i = threadIdx.x;          // row index, blockDim.x == L
    const int wv = i >> 6, ln = i & 63;
    const int l = lengths[b];
    const float rmarg = 1.0f / (float)l;
    const int base = b * L + i;

    const float inv_nx = 1.0f / fmaxf(sqrtf(xn2[base]), 1e-5f);
    inv_ny[i] = 1.0f / fmaxf(sqrtf(yn2[base]), 1e-5f);
    u[i] = 0.f;
    __syncthreads();

    // Build band M and P0 = exp(-lam*M)*mm
    float psum = 0.f;
#pragma unroll
    for (int o = 0; o < 5; ++o) {
        int j = i + o - 2;
        float M = 0.f, P = 0.f;
        if (j >= 0 && j < L && i < l && j < l) {
            M = 1.0f - dots[base * 5 + o] * inv_nx * inv_ny[j];
            P = expf(-LAM_F * M);
        }
        Mb[i * 5 + o] = M;
        Pb[i * 5 + o] = P;
        psum += P;
    }
    // P /= sum(P)  (block reduction)
    psum = wave_reduce_sum(psum);
    if (ln == 0) red[wv] = psum;
    __syncthreads();
    float total = 0.f;
#pragma unroll
    for (int k = 0; k < 16; ++k) total += red[k];
    __syncthreads();
    const float inv_total = 1.0f / total;
#pragma unroll
    for (int o = 0; o < 5; ++o) Pb[i * 5 + o] *= inv_total;

    for (int it = 0; it < 10; ++it) {
        // usum = row sums (own row only — no cross-thread read)
        float us = Pb[i * 5 + 0] + Pb[i * 5 + 1] + Pb[i * 5 + 2] + Pb[i * 5 + 3] + Pb[i * 5 + 4];
        float diff = fabsf(u[i] - us);
#pragma unroll
        for (int m = 1; m < 64; m <<= 1) diff = fmaxf(diff, __shfl_xor(diff, m, 64));
        if (ln == 0) red[wv] = diff;
        __syncthreads();
        float maxdiff = red[0];
#pragma unroll
        for (int k = 1; k < 16; ++k) maxdiff = fmaxf(maxdiff, red[k]);
        __syncthreads();
        if (maxdiff <= EPS_F) break;   // cond false -> P,u frozen forever

        u[i] = us;
        const float sr = (i < l) ? rmarg / us : 0.f;   // scale_r (masked)
#pragma unroll
        for (int o = 0; o < 5; ++o) Pb[i * 5 + o] *= sr;
        __syncthreads();               // P1 complete before column sums

        // s[j=i] = sum over rows rr in [i-2, i+2] of P1[rr][i]
        float s = 0.f;
#pragma unroll
        for (int d = -2; d <= 2; ++d) {
            int rr = i + d;
            if (rr >= 0 && rr < L) s += Pb[rr * 5 + (2 - d)];
        }
        __syncthreads();               // all col-sum reads done before P2 writes
        const float sc = (i < l) ? rmarg / s : 0.f;    // applied along ROWS (faithful)
#pragma unroll
        for (int o = 0; o < 5; ++o) Pb[i * 5 + o] *= sc;
        __syncthreads();
    }

    // Final: rowsum, cost, pre-divided output band
    const float rsum = Pb[i * 5 + 0] + Pb[i * 5 + 1] + Pb[i * 5 + 2] + Pb[i * 5 + 3] + Pb[i * 5 + 4];
    rs[i] = (i < l) ? rsum : 1.0f;
    float cp = 0.f;
#pragma unroll
    for (int o = 0; o < 5; ++o) cp += Pb[i * 5 + o] * Mb[i * 5 + o];
    cp = wave_reduce_sum(cp);
    if (ln == 0) red[wv] = cp;
    __syncthreads();                   // red ready AND rs[] visible
    if (i == 0) {
        float cost = 0.f;
#pragma unroll
        for (int k = 0; k < 16; ++k) cost += red[k];
        cost_out[b] = cost;
    }
#pragma unroll
    for (int o = 0; o < 5; ++o) {
        int j = i + o - 2;
        int jc = min(max(j, 0), L - 1);
        // P_norm[i][j] = P[i][j] / rs[j]  (column-indexed rowsum, faithful)
        oband[base * 5 + o] = Pb[i * 5 + o] / rs[jc];
    }
}

// Kernel B: materialize the (B, L, L) output. One float4 per thread; zeros
// everywhere except where [j0, j0+3] intersects the band [i-2, i+2].
__global__ void __launch_bounds__(256) write_kernel(
        const float* __restrict__ oband, float* __restrict__ out) {
    const int t = blockIdx.x * 256 + threadIdx.x;   // < B*L*L/4 = 8388608
    const int b = t >> 18;                          // L*L/4 = 2^18
    const int rem = t & 262143;
    const int i = rem >> 8;                         // L/4 = 256 float4 per row
    const int j0 = (rem & 255) << 2;
    float4 v = make_float4(0.f, 0.f, 0.f, 0.f);
    if (j0 + 3 >= i - 2 && j0 <= i + 2) {
        const float* ob = oband + (size_t)((b << 10) + i) * 5;
        float vv[4];
#pragma unroll
        for (int k = 0; k < 4; ++k) {
            int o = j0 + k - i;
            vv[k] = (o >= -2 && o <= 2) ? ob[o + 2] : 0.f;
        }
        v = make_float4(vv[0], vv[1], vv[2], vv[3]);
    }
    ((float4*)out)[t] = v;
}

extern "C" void kernel_launch(void* const* d_in, const int* in_sizes, int n_in,
                              void* d_out, int out_size, void* d_ws, size_t ws_size,
                              hipStream_t stream) {
    const float* m1 = (const float*)d_in[0];
    const float* m2 = (const float*)d_in[1];
    const int* lengths = (const int*)d_in[2];
    float* out = (float*)d_out;
    float* ws = (float*)d_ws;

    float* dots  = ws;                      // B*L*5
    float* xn2   = dots + NB * L * 5;       // B*L
    float* yn2   = xn2 + NB * L;            // B*L
    float* oband = yn2 + NB * L;            // B*L*5

    norms_dots_kernel<<<NB * (L / 4), 256, 0, stream>>>(m1, m2, dots, xn2, yn2);
    sinkhorn_kernel<<<NB, L, 0, stream>>>(dots, xn2, yn2, lengths, oband,
                                          out + (size_t)NB * L * L);
    write_kernel<<<(NB * L * L / 4) / 256, 256, 0, stream>>>(oband, out);
}